// Round 1
// baseline (1259.422 us; speedup 1.0000x reference)
//
#include <hip/hip_runtime.h>
#include <math.h>

// Problem dims (fixed by the reference): T=4, B=64, N=256, D=512.
// GEMM rows r = (n*B+b)*T + t  == natural row order of mx [N,B,T,D] -> A = mx.
namespace {
constexpr int TDIM = 4, BDIM = 64, NDIM = 256, DDIM = 512;
constexpr int MROWS = 65536;               // N*B*T
constexpr long long BND = 8388608LL;       // B*N*D
constexpr double BN_EPS = 1e-5;

// GEMM tiling: 64 rows x 128 cols per block, K-chunk 32, 256 threads,
// each thread 4 rows x 8 cols of f64 accumulators.
constexpr int BM = 64, BNT = 128, BK = 32;
constexpr int APITCH = BK + 2;    // 34  (f64 [row][d], padded)
constexpr int WPITCH = BNT + 4;   // 132 (f64 [d][e], padded, 16B-aligned reads)
constexpr int LDS_BYTES = (BM * APITCH + BK * WPITCH) * 8;  // 51200 B < 64KB
}

// MODE 0: GEMM -> per-channel sum/sumsq only (h discarded)
// MODE 1: GEMM -> store h (f64) + per-channel sum/sumsq
// MODE 2: GEMM -> BN(scale/shift) + LIF over t in registers + out = s ? x : 0
template<int MODE>
__global__ __launch_bounds__(256)
void gemm_k(const float* __restrict__ mx, const float* __restrict__ Wm,
            double* __restrict__ hbuf, double* __restrict__ sums,
            const double* __restrict__ scale, const double* __restrict__ shiftv,
            const float* __restrict__ x, float* __restrict__ out)
{
    __shared__ __align__(16) char smem[LDS_BYTES];
    double (*Ald)[APITCH] = reinterpret_cast<double(*)[APITCH]>(smem);
    double (*Wld)[WPITCH] = reinterpret_cast<double(*)[WPITCH]>(smem + (size_t)BM * APITCH * 8);

    const int tid  = threadIdx.x;
    const int rb   = blockIdx.x >> 2;   // 1024 row-blocks
    const int cb   = blockIdx.x & 3;    // 4 col-blocks
    const int row0 = rb * BM;
    const int col0 = cb * BNT;

    // Loaders: A tile 64x32 (8 f32/thread), W tile 128x32 (16 f32/thread)
    const int arow = tid >> 2;
    const int ak   = (tid & 3) * 8;
    const int erow = tid >> 1;
    const int wk   = (tid & 1) * 16;

    const float* aSrc = mx + (size_t)(row0 + arow) * DDIM;
    const float* wSrc = Wm + (size_t)(col0 + erow) * DDIM;

    const int rg = tid >> 4;   // 16 row groups  * 4 rows
    const int cg = tid & 15;   // 16 col groups  * 8 cols

    double acc[4][8];
#pragma unroll
    for (int i = 0; i < 4; ++i)
#pragma unroll
        for (int j = 0; j < 8; ++j) acc[i][j] = 0.0;

    for (int kk = 0; kk < DDIM; kk += BK) {
        const float4 a0 = *(const float4*)(aSrc + kk + ak);
        const float4 a1 = *(const float4*)(aSrc + kk + ak + 4);
        const float4 w0 = *(const float4*)(wSrc + kk + wk);
        const float4 w1 = *(const float4*)(wSrc + kk + wk + 4);
        const float4 w2 = *(const float4*)(wSrc + kk + wk + 8);
        const float4 w3 = *(const float4*)(wSrc + kk + wk + 12);
        __syncthreads();
        // A staged as f64 [row][d]
        Ald[arow][ak + 0] = (double)a0.x; Ald[arow][ak + 1] = (double)a0.y;
        Ald[arow][ak + 2] = (double)a0.z; Ald[arow][ak + 3] = (double)a0.w;
        Ald[arow][ak + 4] = (double)a1.x; Ald[arow][ak + 5] = (double)a1.y;
        Ald[arow][ak + 6] = (double)a1.z; Ald[arow][ak + 7] = (double)a1.w;
        // W staged transposed as f64 [d][e]
        const float wf[16] = {w0.x, w0.y, w0.z, w0.w, w1.x, w1.y, w1.z, w1.w,
                              w2.x, w2.y, w2.z, w2.w, w3.x, w3.y, w3.z, w3.w};
#pragma unroll
        for (int q = 0; q < 16; ++q) Wld[wk + q][erow] = (double)wf[q];
        __syncthreads();

#pragma unroll 4
        for (int d = 0; d < BK; ++d) {
            double a[4], w[8];
#pragma unroll
            for (int i = 0; i < 4; ++i) a[i] = Ald[rg * 4 + i][d];
#pragma unroll
            for (int j = 0; j < 8; ++j) w[j] = Wld[d][cg * 8 + j];
#pragma unroll
            for (int i = 0; i < 4; ++i)
#pragma unroll
                for (int j = 0; j < 8; ++j)
                    acc[i][j] = fma(a[i], w[j], acc[i][j]);
        }
    }

    if (MODE == 1) {
#pragma unroll
        for (int i = 0; i < 4; ++i) {
            double* dst = hbuf + (size_t)(row0 + rg * 4 + i) * DDIM + col0 + cg * 8;
#pragma unroll
            for (int j = 0; j < 8; ++j) dst[j] = acc[i][j];
        }
    }

    if (MODE <= 1) {
        // Per-channel partial sums: reduce 64 rows of this block, atomic to global.
        __syncthreads();
        double* scr = reinterpret_cast<double*>(smem);   // [128][16] sum, [128][16] sq
#pragma unroll
        for (int j = 0; j < 8; ++j) {
            const double s = acc[0][j] + acc[1][j] + acc[2][j] + acc[3][j];
            const double q = acc[0][j]*acc[0][j] + acc[1][j]*acc[1][j]
                           + acc[2][j]*acc[2][j] + acc[3][j]*acc[3][j];
            scr[(cg * 8 + j) * 16 + rg] = s;
            scr[2048 + (cg * 8 + j) * 16 + rg] = q;
        }
        __syncthreads();
        if (tid < 128) {
            double s = 0.0, q = 0.0;
#pragma unroll
            for (int r = 0; r < 16; ++r) {
                s += scr[tid * 16 + r];
                q += scr[2048 + tid * 16 + r];
            }
            atomicAdd(&sums[col0 + tid], s);
            atomicAdd(&sums[512 + col0 + tid], q);
        }
    }

    if (MODE == 2) {
        // Thread's 4 rows are the 4 timesteps of one (n,b) pair: LIF in registers.
        const int p  = rb * 16 + rg;     // p = n*B + b
        const int nn = p >> 6;
        const int bb = p & 63;
#pragma unroll
        for (int j = 0; j < 8; ++j) {
            const int e = col0 + cg * 8 + j;
            const double sc = scale[e];
            const double sh = shiftv[e];
            const size_t basex = (size_t)bb * (NDIM * DDIM) + (size_t)nn * DDIM + e;
            double v = 0.0;
#pragma unroll
            for (int t = 0; t < 4; ++t) {
                const double hn = fma(acc[t][j], sc, sh);   // BN folded: h*scale+shift
                v = v + (hn - v) / 2.0;                     // v += (x - v)/tau, tau=2
                const bool s = (v - 0.5) >= 0.0;            // H(v - v_th)
                const size_t xi = (size_t)t * BND + basex;
                out[xi] = s ? x[xi] : 0.0f;
                if (s) v = 0.0;                             // hard reset
            }
        }
    }
}

__global__ void zero_k(double* sums)
{
    const int i = blockIdx.x * 256 + threadIdx.x;
    if (i < 1024) sums[i] = 0.0;
}

__global__ void stat_k(const double* __restrict__ sums,
                       const float* __restrict__ gamma, const float* __restrict__ beta,
                       double* __restrict__ scale, double* __restrict__ shiftv)
{
    const int e = blockIdx.x * 256 + threadIdx.x;
    if (e < 512) {
        const double mean = sums[e] * (1.0 / 65536.0);
        const double msq  = sums[512 + e] * (1.0 / 65536.0);
        const double var  = msq - mean * mean;               // biased var
        const double inv  = 1.0 / sqrt(var + BN_EPS);
        const double g    = (double)gamma[e] * inv;
        scale[e]  = g;
        shiftv[e] = (double)beta[e] - mean * g;
    }
}

__global__ __launch_bounds__(256)
void lifh_k(const double* __restrict__ hbuf, const double* __restrict__ scale,
            const double* __restrict__ shiftv, const float* __restrict__ x,
            float* __restrict__ out)
{
    const size_t i = (size_t)blockIdx.x * 256 + threadIdx.x;   // < B*N*D
    const int e  = (int)(i & 511);
    const size_t p = i >> 9;            // p = n*B + b
    const int nn = (int)(p >> 6);
    const int bb = (int)(p & 63);
    const double sc = scale[e];
    const double sh = shiftv[e];
    const double* hp = hbuf + p * 2048 + e;       // rows p*4+t, stride 512
    const size_t basex = (size_t)bb * (NDIM * DDIM) + (size_t)nn * DDIM + e;
    double v = 0.0;
#pragma unroll
    for (int t = 0; t < 4; ++t) {
        const double hn = fma(hp[(size_t)t * 512], sc, sh);
        v = v + (hn - v) / 2.0;
        const bool s = (v - 0.5) >= 0.0;
        const size_t xi = (size_t)t * BND + basex;
        out[xi] = s ? x[xi] : 0.0f;
        if (s) v = 0.0;
    }
}

extern "C" void kernel_launch(void* const* d_in, const int* in_sizes, int n_in,
                              void* d_out, int out_size, void* d_ws, size_t ws_size,
                              hipStream_t stream)
{
    const float* x     = (const float*)d_in[0];
    const float* mx    = (const float*)d_in[1];
    const float* Wm    = (const float*)d_in[2];
    const float* gamma = (const float*)d_in[3];
    const float* beta  = (const float*)d_in[4];
    float* out = (float*)d_out;

    char* ws = (char*)d_ws;
    double* sums   = (double*)ws;            // [1024]: sum[512], sumsq[512]
    double* scale  = (double*)(ws + 8192);   // [512]
    double* shiftv = scale + 512;            // [512]
    double* hbuf   = (double*)(ws + 16384);  // [65536*512] f64 if it fits

    const size_t need_h = (size_t)16384 + (size_t)MROWS * DDIM * 8;
    const bool big = ws_size >= need_h;

    hipLaunchKernelGGL(zero_k, dim3(4), dim3(256), 0, stream, sums);

    if (big) {
        hipLaunchKernelGGL((gemm_k<1>), dim3(4096), dim3(256), 0, stream,
                           mx, Wm, hbuf, sums, nullptr, nullptr, nullptr, nullptr);
        hipLaunchKernelGGL(stat_k, dim3(2), dim3(256), 0, stream,
                           sums, gamma, beta, scale, shiftv);
        hipLaunchKernelGGL(lifh_k, dim3(32768), dim3(256), 0, stream,
                           hbuf, scale, shiftv, x, out);
    } else {
        hipLaunchKernelGGL((gemm_k<0>), dim3(4096), dim3(256), 0, stream,
                           mx, Wm, nullptr, sums, nullptr, nullptr, nullptr, nullptr);
        hipLaunchKernelGGL(stat_k, dim3(2), dim3(256), 0, stream,
                           sums, gamma, beta, scale, shiftv);
        hipLaunchKernelGGL((gemm_k<2>), dim3(4096), dim3(256), 0, stream,
                           mx, Wm, nullptr, nullptr, scale, shiftv, x, out);
    }
}

// Round 2
// 857.805 us; speedup vs baseline: 1.4682x; 1.4682x over previous
//
#include <hip/hip_runtime.h>
#include <math.h>

// Problem dims (fixed by the reference): T=4, B=64, N=256, D=512.
// GEMM rows r = (n*B+b)*T + t  == natural row order of mx [N,B,T,D] -> A = mx.
namespace {
constexpr int TDIM = 4, BDIM = 64, NDIM = 256, DDIM = 512;
constexpr int MROWS = 65536;               // N*B*T
constexpr long long BND = 8388608LL;       // B*N*D
constexpr double BN_EPS = 1e-5;

// ---- old (fallback) tiling: 64x128, BK=32 ----
constexpr int BM = 64, BNT = 128, BK = 32;
constexpr int APITCH = BK + 2;    // 34
constexpr int WPITCH = BNT + 4;   // 132
constexpr int LDS_BYTES = (BM * APITCH + BK * WPITCH) * 8;  // 51200 B

// ---- new (big path) tiling: 128x128, BK=16, 8x8 per thread ----
constexpr int BM2 = 128, BN2 = 128, BK2 = 16;
constexpr int AP2 = BM2 + 2;      // 130 doubles pitch, Atr[d][row]
constexpr int WP2 = BN2 + 2;      // 130 doubles pitch, Wt[d][col]
constexpr int STAGE_BYTES = (BK2 * AP2 + BK2 * WP2) * 8;    // 33280 B
constexpr int SCR_BYTES = 128 * 16 * 8 * 2;                 // 32768 B
constexpr int LDS2 = STAGE_BYTES > SCR_BYTES ? STAGE_BYTES : SCR_BYTES;
}

// ============ new 128x128 f64 GEMM, fused per-channel sum/sumsq ============
__global__ __launch_bounds__(256)
void gemm2_k(const float* __restrict__ mx, const float* __restrict__ Wm,
             double* __restrict__ hbuf, double* __restrict__ sums)
{
    __shared__ __align__(16) char smem[LDS2];
    double* Atr = reinterpret_cast<double*>(smem);                       // [BK2][AP2]
    double* Wt  = reinterpret_cast<double*>(smem) + BK2 * AP2;           // [BK2][WP2]

    const int tid  = threadIdx.x;
    const int rb   = blockIdx.x >> 2;   // 512 row-blocks
    const int cb   = blockIdx.x & 3;    // 4 col-blocks (consecutive bids share A tile)
    const int row0 = rb * BM2;
    const int col0 = cb * BN2;

    const int tx = tid & 15;            // col group
    const int ty = tid >> 4;            // row group (0..15)

    // Loaders: each thread loads 8 consecutive f32 of one A row and one W row.
    const int lr = tid >> 1;            // 0..127
    const int dd = (tid & 1) * 8;       // 0 or 8
    const float* aSrc = mx + (size_t)(row0 + lr) * DDIM + dd;
    const float* wSrc = Wm + (size_t)(col0 + lr) * DDIM + dd;

    double acc[8][8];
#pragma unroll
    for (int i = 0; i < 8; ++i)
#pragma unroll
        for (int j = 0; j < 8; ++j) acc[i][j] = 0.0;

    for (int kk = 0; kk < DDIM; kk += BK2) {
        const float4 a0 = *(const float4*)(aSrc + kk);
        const float4 a1 = *(const float4*)(aSrc + kk + 4);
        const float4 w0 = *(const float4*)(wSrc + kk);
        const float4 w1 = *(const float4*)(wSrc + kk + 4);
        __syncthreads();
        // stage K-major as f64
        Atr[(dd + 0) * AP2 + lr] = (double)a0.x;
        Atr[(dd + 1) * AP2 + lr] = (double)a0.y;
        Atr[(dd + 2) * AP2 + lr] = (double)a0.z;
        Atr[(dd + 3) * AP2 + lr] = (double)a0.w;
        Atr[(dd + 4) * AP2 + lr] = (double)a1.x;
        Atr[(dd + 5) * AP2 + lr] = (double)a1.y;
        Atr[(dd + 6) * AP2 + lr] = (double)a1.z;
        Atr[(dd + 7) * AP2 + lr] = (double)a1.w;
        Wt[(dd + 0) * WP2 + lr] = (double)w0.x;
        Wt[(dd + 1) * WP2 + lr] = (double)w0.y;
        Wt[(dd + 2) * WP2 + lr] = (double)w0.z;
        Wt[(dd + 3) * WP2 + lr] = (double)w0.w;
        Wt[(dd + 4) * WP2 + lr] = (double)w1.x;
        Wt[(dd + 5) * WP2 + lr] = (double)w1.y;
        Wt[(dd + 6) * WP2 + lr] = (double)w1.z;
        Wt[(dd + 7) * WP2 + lr] = (double)w1.w;
        __syncthreads();

#pragma unroll
        for (int d = 0; d < BK2; ++d) {
            double2 ar[4], wr[4];
#pragma unroll
            for (int g = 0; g < 4; ++g) {
                ar[g] = *(const double2*)&Atr[d * AP2 + 2 * ty + 32 * g];
                wr[g] = *(const double2*)&Wt [d * WP2 + 2 * tx + 32 * g];
            }
#pragma unroll
            for (int i2 = 0; i2 < 4; ++i2) {
                const double au = ar[i2].x, av = ar[i2].y;
#pragma unroll
                for (int j2 = 0; j2 < 4; ++j2) {
                    acc[2*i2+0][2*j2+0] = fma(au, wr[j2].x, acc[2*i2+0][2*j2+0]);
                    acc[2*i2+0][2*j2+1] = fma(au, wr[j2].y, acc[2*i2+0][2*j2+1]);
                    acc[2*i2+1][2*j2+0] = fma(av, wr[j2].x, acc[2*i2+1][2*j2+0]);
                    acc[2*i2+1][2*j2+1] = fma(av, wr[j2].y, acc[2*i2+1][2*j2+1]);
                }
            }
        }
    }

    // ---- store h (f64), coalesced 256 B per (i, j2) across 16 lanes ----
#pragma unroll
    for (int i = 0; i < 8; ++i) {
        const int r = 2 * ty + 32 * (i >> 1) + (i & 1);
        double* dst = hbuf + (size_t)(row0 + r) * DDIM + col0 + 2 * tx;
#pragma unroll
        for (int j2 = 0; j2 < 4; ++j2) {
            double2 v; v.x = acc[i][2*j2]; v.y = acc[i][2*j2+1];
            *(double2*)(dst + 32 * j2) = v;
        }
    }

    // ---- per-channel partial sums ----
    __syncthreads();
    double* scr = reinterpret_cast<double*>(smem);   // [128][16] sum, then sq
#pragma unroll
    for (int j = 0; j < 8; ++j) {
        const int c = 2 * tx + 32 * (j >> 1) + (j & 1);
        double s = 0.0, q = 0.0;
#pragma unroll
        for (int i = 0; i < 8; ++i) { s += acc[i][j]; q += acc[i][j] * acc[i][j]; }
        scr[c * 16 + ty] = s;
        scr[2048 + c * 16 + ty] = q;
    }
    __syncthreads();
    if (tid < 128) {
        double s = 0.0, q = 0.0;
#pragma unroll
        for (int r = 0; r < 16; ++r) {
            s += scr[tid * 16 + r];
            q += scr[2048 + tid * 16 + r];
        }
        atomicAdd(&sums[col0 + tid], s);
        atomicAdd(&sums[512 + col0 + tid], q);
    }
}

// ============ fallback small-ws kernel (unchanged from R1) ============
template<int MODE>
__global__ __launch_bounds__(256)
void gemm_k(const float* __restrict__ mx, const float* __restrict__ Wm,
            double* __restrict__ hbuf, double* __restrict__ sums,
            const double* __restrict__ scale, const double* __restrict__ shiftv,
            const float* __restrict__ x, float* __restrict__ out)
{
    __shared__ __align__(16) char smem[LDS_BYTES];
    double (*Ald)[APITCH] = reinterpret_cast<double(*)[APITCH]>(smem);
    double (*Wld)[WPITCH] = reinterpret_cast<double(*)[WPITCH]>(smem + (size_t)BM * APITCH * 8);

    const int tid  = threadIdx.x;
    const int rb   = blockIdx.x >> 2;
    const int cb   = blockIdx.x & 3;
    const int row0 = rb * BM;
    const int col0 = cb * BNT;

    const int arow = tid >> 2;
    const int ak   = (tid & 3) * 8;
    const int erow = tid >> 1;
    const int wk   = (tid & 1) * 16;

    const float* aSrc = mx + (size_t)(row0 + arow) * DDIM;
    const float* wSrc = Wm + (size_t)(col0 + erow) * DDIM;

    const int rg = tid >> 4;
    const int cg = tid & 15;

    double acc[4][8];
#pragma unroll
    for (int i = 0; i < 4; ++i)
#pragma unroll
        for (int j = 0; j < 8; ++j) acc[i][j] = 0.0;

    for (int kk = 0; kk < DDIM; kk += BK) {
        const float4 a0 = *(const float4*)(aSrc + kk + ak);
        const float4 a1 = *(const float4*)(aSrc + kk + ak + 4);
        const float4 w0 = *(const float4*)(wSrc + kk + wk);
        const float4 w1 = *(const float4*)(wSrc + kk + wk + 4);
        const float4 w2 = *(const float4*)(wSrc + kk + wk + 8);
        const float4 w3 = *(const float4*)(wSrc + kk + wk + 12);
        __syncthreads();
        Ald[arow][ak + 0] = (double)a0.x; Ald[arow][ak + 1] = (double)a0.y;
        Ald[arow][ak + 2] = (double)a0.z; Ald[arow][ak + 3] = (double)a0.w;
        Ald[arow][ak + 4] = (double)a1.x; Ald[arow][ak + 5] = (double)a1.y;
        Ald[arow][ak + 6] = (double)a1.z; Ald[arow][ak + 7] = (double)a1.w;
        const float wf[16] = {w0.x, w0.y, w0.z, w0.w, w1.x, w1.y, w1.z, w1.w,
                              w2.x, w2.y, w2.z, w2.w, w3.x, w3.y, w3.z, w3.w};
#pragma unroll
        for (int q = 0; q < 16; ++q) Wld[wk + q][erow] = (double)wf[q];
        __syncthreads();

#pragma unroll 4
        for (int d = 0; d < BK; ++d) {
            double a[4], w[8];
#pragma unroll
            for (int i = 0; i < 4; ++i) a[i] = Ald[rg * 4 + i][d];
#pragma unroll
            for (int j = 0; j < 8; ++j) w[j] = Wld[d][cg * 8 + j];
#pragma unroll
            for (int i = 0; i < 4; ++i)
#pragma unroll
                for (int j = 0; j < 8; ++j)
                    acc[i][j] = fma(a[i], w[j], acc[i][j]);
        }
    }

    if (MODE <= 1) {
        __syncthreads();
        double* scr = reinterpret_cast<double*>(smem);
#pragma unroll
        for (int j = 0; j < 8; ++j) {
            const double s = acc[0][j] + acc[1][j] + acc[2][j] + acc[3][j];
            const double q = acc[0][j]*acc[0][j] + acc[1][j]*acc[1][j]
                           + acc[2][j]*acc[2][j] + acc[3][j]*acc[3][j];
            scr[(cg * 8 + j) * 16 + rg] = s;
            scr[2048 + (cg * 8 + j) * 16 + rg] = q;
        }
        __syncthreads();
        if (tid < 128) {
            double s = 0.0, q = 0.0;
#pragma unroll
            for (int r = 0; r < 16; ++r) {
                s += scr[tid * 16 + r];
                q += scr[2048 + tid * 16 + r];
            }
            atomicAdd(&sums[col0 + tid], s);
            atomicAdd(&sums[512 + col0 + tid], q);
        }
    }

    if (MODE == 2) {
        const int p  = rb * 16 + rg;
        const int nn = p >> 6;
        const int bb = p & 63;
#pragma unroll
        for (int j = 0; j < 8; ++j) {
            const int e = col0 + cg * 8 + j;
            const double sc = scale[e];
            const double sh = shiftv[e];
            const size_t basex = (size_t)bb * (NDIM * DDIM) + (size_t)nn * DDIM + e;
            double v = 0.0;
#pragma unroll
            for (int t = 0; t < 4; ++t) {
                const double hn = fma(acc[t][j], sc, sh);
                v = v + (hn - v) / 2.0;
                const bool s = (v - 0.5) >= 0.0;
                const size_t xi = (size_t)t * BND + basex;
                out[xi] = s ? x[xi] : 0.0f;
                if (s) v = 0.0;
            }
        }
    }
}

__global__ void zero_k(double* sums)
{
    const int i = blockIdx.x * 256 + threadIdx.x;
    if (i < 1024) sums[i] = 0.0;
}

__global__ void stat_k(const double* __restrict__ sums,
                       const float* __restrict__ gamma, const float* __restrict__ beta,
                       double* __restrict__ scale, double* __restrict__ shiftv)
{
    const int e = blockIdx.x * 256 + threadIdx.x;
    if (e < 512) {
        const double mean = sums[e] * (1.0 / 65536.0);
        const double msq  = sums[512 + e] * (1.0 / 65536.0);
        const double var  = msq - mean * mean;
        const double inv  = 1.0 / sqrt(var + BN_EPS);
        const double g    = (double)gamma[e] * inv;
        scale[e]  = g;
        shiftv[e] = (double)beta[e] - mean * g;
    }
}

__global__ __launch_bounds__(256)
void lifh_k(const double* __restrict__ hbuf, const double* __restrict__ scale,
            const double* __restrict__ shiftv, const float* __restrict__ x,
            float* __restrict__ out)
{
    const size_t i = (size_t)blockIdx.x * 256 + threadIdx.x;   // < B*N*D
    const int e  = (int)(i & 511);
    const size_t p = i >> 9;
    const int nn = (int)(p >> 6);
    const int bb = (int)(p & 63);
    const double sc = scale[e];
    const double sh = shiftv[e];
    const double* hp = hbuf + p * 2048 + e;
    const size_t basex = (size_t)bb * (NDIM * DDIM) + (size_t)nn * DDIM + e;
    double v = 0.0;
#pragma unroll
    for (int t = 0; t < 4; ++t) {
        const double hn = fma(hp[(size_t)t * 512], sc, sh);
        v = v + (hn - v) / 2.0;
        const bool s = (v - 0.5) >= 0.0;
        const size_t xi = (size_t)t * BND + basex;
        out[xi] = s ? x[xi] : 0.0f;
        if (s) v = 0.0;
    }
}

extern "C" void kernel_launch(void* const* d_in, const int* in_sizes, int n_in,
                              void* d_out, int out_size, void* d_ws, size_t ws_size,
                              hipStream_t stream)
{
    const float* x     = (const float*)d_in[0];
    const float* mx    = (const float*)d_in[1];
    const float* Wm    = (const float*)d_in[2];
    const float* gamma = (const float*)d_in[3];
    const float* beta  = (const float*)d_in[4];
    float* out = (float*)d_out;

    char* ws = (char*)d_ws;
    double* sums   = (double*)ws;            // [1024]
    double* scale  = (double*)(ws + 8192);   // [512]
    double* shiftv = scale + 512;            // [512]
    double* hbuf   = (double*)(ws + 16384);  // [65536*512] f64 if it fits

    const size_t need_h = (size_t)16384 + (size_t)MROWS * DDIM * 8;
    const bool big = ws_size >= need_h;

    hipLaunchKernelGGL(zero_k, dim3(4), dim3(256), 0, stream, sums);

    if (big) {
        hipLaunchKernelGGL(gemm2_k, dim3(2048), dim3(256), 0, stream,
                           mx, Wm, hbuf, sums);
        hipLaunchKernelGGL(stat_k, dim3(2), dim3(256), 0, stream,
                           sums, gamma, beta, scale, shiftv);
        hipLaunchKernelGGL(lifh_k, dim3(32768), dim3(256), 0, stream,
                           hbuf, scale, shiftv, x, out);
    } else {
        hipLaunchKernelGGL((gemm_k<0>), dim3(4096), dim3(256), 0, stream,
                           mx, Wm, nullptr, sums, nullptr, nullptr, nullptr, nullptr);
        hipLaunchKernelGGL(stat_k, dim3(2), dim3(256), 0, stream,
                           sums, gamma, beta, scale, shiftv);
        hipLaunchKernelGGL((gemm_k<2>), dim3(4096), dim3(256), 0, stream,
                           mx, Wm, nullptr, nullptr, scale, shiftv, x, out);
    }
}

// Round 4
// 820.452 us; speedup vs baseline: 1.5350x; 1.0455x over previous
//
#include <hip/hip_runtime.h>
#include <math.h>

// Problem dims (fixed): T=4, B=64, N=256, D=512.
// GEMM rows r = (n*B+b)*T + t == natural row order of mx [N,B,T,D] -> A = mx.
namespace {
constexpr int TDIM = 4, BDIM = 64, NDIM = 256, DDIM = 512;
constexpr int MROWS = 65536;               // N*B*T
constexpr long long BND = 8388608LL;       // B*N*D
constexpr double BN_EPS = 1e-5;

// ---- fallback tiling (small-ws path, unchanged from R1) ----
constexpr int BM = 64, BNT = 128, BK = 32;
constexpr int APITCH = BK + 2;
constexpr int WPITCH = BNT + 4;
constexpr int LDS_BYTES = (BM * APITCH + BK * WPITCH) * 8;

// ---- f64-MFMA path: 128x128 block, 4 waves of 64x64, K-chunk 16 ----
constexpr int BM3 = 128, BN3 = 128, BK3 = 16;
constexpr int AP3 = BM3 + 1;   // 129 doubles pitch, K-major [k][row]
// LDS: 2 * 16 * 129 * 8 = 33,024 B  (< 64 KiB; 4 blocks/CU by LDS)
}

typedef double d4 __attribute__((ext_vector_type(4)));

// ======= probe: discover D row mapping of v_mfma_f64_16x16x4f64 =======
// A[m][k] supplied as value m (lane = m + 16k), B == 1  ->  D[i][j] = 4*i.
// rowmap[lane*4 + r] = i  for the element acc[r] of this lane.
__global__ void probe_k(double* __restrict__ rowmap)
{
    const int l = threadIdx.x;           // 64 threads = 1 wave
    d4 z = {0.0, 0.0, 0.0, 0.0};
    d4 dr = __builtin_amdgcn_mfma_f64_16x16x4f64((double)(l & 15), 1.0, z, 0, 0, 0);
#pragma unroll
    for (int r = 0; r < 4; ++r)
        rowmap[l * 4 + r] = dr[r] * 0.25;
}

// ================= f64 MFMA GEMM + fused per-channel stats =================
__global__ __launch_bounds__(256)
void gemm3_k(const float* __restrict__ mx, const float* __restrict__ Wm,
             double* __restrict__ hbuf, double* __restrict__ sums,
             const double* __restrict__ rowmap)
{
    __shared__ double Atr[BK3 * AP3];   // [k][row]
    __shared__ double Wt [BK3 * AP3];   // [k][col]

    const int tid  = threadIdx.x;
    const int rb   = blockIdx.x >> 2;   // 512 row-blocks
    const int cb   = blockIdx.x & 3;    // 4 col-blocks (consecutive share A-tile in L2)
    const int row0 = rb * BM3;
    const int col0 = cb * BN3;

    const int w  = tid >> 6;            // wave 0..3
    const int l  = tid & 63;
    const int wr = w >> 1;              // wave row (0..1) -> 64-row slab
    const int wc = w & 1;               // wave col (0..1) -> 64-col slab
    const int lr = l & 15;              // m/n within 16-tile (A,B lane = idx + 16k)
    const int kq = l >> 4;              // k index within K=4 slice

    // runtime-discovered D row mapping (same for every wave)
    int irow[4];
#pragma unroll
    for (int r = 0; r < 4; ++r)
        irow[r] = (int)rowmap[l * 4 + r];

    // Loaders: thread t loads 8 consecutive f32 of one A row and one W row.
    const int arow = tid >> 1;          // 0..127
    const int aks  = (tid & 1) * 8;     // 0 or 8
    const float* aSrc = mx + (size_t)(row0 + arow) * DDIM + aks;
    const float* wSrc = Wm + (size_t)(col0 + arow) * DDIM + aks;

    d4 acc[4][4];
#pragma unroll
    for (int i = 0; i < 4; ++i)
#pragma unroll
        for (int j = 0; j < 4; ++j) acc[i][j] = (d4){0.0, 0.0, 0.0, 0.0};

    // prefetch chunk 0
    float4 pa0 = *(const float4*)(aSrc + 0);
    float4 pa1 = *(const float4*)(aSrc + 4);
    float4 pw0 = *(const float4*)(wSrc + 0);
    float4 pw1 = *(const float4*)(wSrc + 4);

    for (int kk = 0; kk < DDIM; kk += BK3) {
        __syncthreads();   // previous chunk's reads done
        Atr[(aks + 0) * AP3 + arow] = (double)pa0.x;
        Atr[(aks + 1) * AP3 + arow] = (double)pa0.y;
        Atr[(aks + 2) * AP3 + arow] = (double)pa0.z;
        Atr[(aks + 3) * AP3 + arow] = (double)pa0.w;
        Atr[(aks + 4) * AP3 + arow] = (double)pa1.x;
        Atr[(aks + 5) * AP3 + arow] = (double)pa1.y;
        Atr[(aks + 6) * AP3 + arow] = (double)pa1.z;
        Atr[(aks + 7) * AP3 + arow] = (double)pa1.w;
        Wt[(aks + 0) * AP3 + arow] = (double)pw0.x;
        Wt[(aks + 1) * AP3 + arow] = (double)pw0.y;
        Wt[(aks + 2) * AP3 + arow] = (double)pw0.z;
        Wt[(aks + 3) * AP3 + arow] = (double)pw0.w;
        Wt[(aks + 4) * AP3 + arow] = (double)pw1.x;
        Wt[(aks + 5) * AP3 + arow] = (double)pw1.y;
        Wt[(aks + 6) * AP3 + arow] = (double)pw1.z;
        Wt[(aks + 7) * AP3 + arow] = (double)pw1.w;
        __syncthreads();

        // prefetch next chunk while this one computes
        if (kk + BK3 < DDIM) {
            pa0 = *(const float4*)(aSrc + kk + BK3 + 0);
            pa1 = *(const float4*)(aSrc + kk + BK3 + 4);
            pw0 = *(const float4*)(wSrc + kk + BK3 + 0);
            pw1 = *(const float4*)(wSrc + kk + BK3 + 4);
        }

#pragma unroll
        for (int ks = 0; ks < BK3 / 4; ++ks) {
            const int kabs = ks * 4 + kq;
            double a[4], b[4];
#pragma unroll
            for (int i = 0; i < 4; ++i)
                a[i] = Atr[kabs * AP3 + 64 * wr + 16 * i + lr];
#pragma unroll
            for (int j = 0; j < 4; ++j)
                b[j] = Wt[kabs * AP3 + 64 * wc + 16 * j + lr];
#pragma unroll
            for (int i = 0; i < 4; ++i)
#pragma unroll
                for (int j = 0; j < 4; ++j)
                    acc[i][j] = __builtin_amdgcn_mfma_f64_16x16x4f64(
                                    a[i], b[j], acc[i][j], 0, 0, 0);
        }
    }

    // ---- store h (f64): col = lane&15 (both layout candidates agree),
    //      row from the runtime-probed map irow[r] ----
#pragma unroll
    for (int i = 0; i < 4; ++i) {
#pragma unroll
        for (int j = 0; j < 4; ++j) {
            const size_t cbase = (size_t)col0 + 64 * wc + 16 * j + lr;
            const size_t rbase = (size_t)row0 + 64 * wr + 16 * i;
#pragma unroll
            for (int r = 0; r < 4; ++r)
                hbuf[(rbase + irow[r]) * DDIM + cbase] = acc[i][j][r];
        }
    }

    // ---- fused per-channel sum/sumsq (row-agnostic) ----
    __syncthreads();                         // done reading Atr/Wt
    double* Ssum = Atr;                      // reuse: [128 cols][8 contributors]
    double* Ssq  = Atr + 1024;
    const int ctr = wr * 4 + kq;             // 0..7
#pragma unroll
    for (int j = 0; j < 4; ++j) {
        const int cloc = 64 * wc + 16 * j + lr;   // 0..127
        double s = 0.0, q = 0.0;
#pragma unroll
        for (int i = 0; i < 4; ++i)
#pragma unroll
            for (int r = 0; r < 4; ++r) {
                const double v = acc[i][j][r];
                s += v;
                q = fma(v, v, q);
            }
        Ssum[cloc * 8 + ctr] = s;
        Ssq [cloc * 8 + ctr] = q;
    }
    __syncthreads();
    if (tid < 128) {
        double s = 0.0, q = 0.0;
#pragma unroll
        for (int c = 0; c < 8; ++c) {
            s += Ssum[tid * 8 + c];
            q += Ssq [tid * 8 + c];
        }
        atomicAdd(&sums[col0 + tid], s);
        atomicAdd(&sums[512 + col0 + tid], q);
    }
}

// ============ fallback small-ws kernel (unchanged from R1) ============
template<int MODE>
__global__ __launch_bounds__(256)
void gemm_k(const float* __restrict__ mx, const float* __restrict__ Wm,
            double* __restrict__ hbuf, double* __restrict__ sums,
            const double* __restrict__ scale, const double* __restrict__ shiftv,
            const float* __restrict__ x, float* __restrict__ out)
{
    __shared__ __align__(16) char smem[LDS_BYTES];
    double (*Ald)[APITCH] = reinterpret_cast<double(*)[APITCH]>(smem);
    double (*Wld)[WPITCH] = reinterpret_cast<double(*)[WPITCH]>(smem + (size_t)BM * APITCH * 8);

    const int tid  = threadIdx.x;
    const int rb   = blockIdx.x >> 2;
    const int cb   = blockIdx.x & 3;
    const int row0 = rb * BM;
    const int col0 = cb * BNT;

    const int arow = tid >> 2;
    const int ak   = (tid & 3) * 8;
    const int erow = tid >> 1;
    const int wk   = (tid & 1) * 16;

    const float* aSrc = mx + (size_t)(row0 + arow) * DDIM;
    const float* wSrc = Wm + (size_t)(col0 + erow) * DDIM;

    const int rg = tid >> 4;
    const int cg = tid & 15;

    double acc[4][8];
#pragma unroll
    for (int i = 0; i < 4; ++i)
#pragma unroll
        for (int j = 0; j < 8; ++j) acc[i][j] = 0.0;

    for (int kk = 0; kk < DDIM; kk += BK) {
        const float4 a0 = *(const float4*)(aSrc + kk + ak);
        const float4 a1 = *(const float4*)(aSrc + kk + ak + 4);
        const float4 w0 = *(const float4*)(wSrc + kk + wk);
        const float4 w1 = *(const float4*)(wSrc + kk + wk + 4);
        const float4 w2 = *(const float4*)(wSrc + kk + wk + 8);
        const float4 w3 = *(const float4*)(wSrc + kk + wk + 12);
        __syncthreads();
        Ald[arow][ak + 0] = (double)a0.x; Ald[arow][ak + 1] = (double)a0.y;
        Ald[arow][ak + 2] = (double)a0.z; Ald[arow][ak + 3] = (double)a0.w;
        Ald[arow][ak + 4] = (double)a1.x; Ald[arow][ak + 5] = (double)a1.y;
        Ald[arow][ak + 6] = (double)a1.z; Ald[arow][ak + 7] = (double)a1.w;
        const float wf[16] = {w0.x, w0.y, w0.z, w0.w, w1.x, w1.y, w1.z, w1.w,
                              w2.x, w2.y, w2.z, w2.w, w3.x, w3.y, w3.z, w3.w};
#pragma unroll
        for (int q = 0; q < 16; ++q) Wld[wk + q][erow] = (double)wf[q];
        __syncthreads();

#pragma unroll 4
        for (int d = 0; d < BK; ++d) {
            double a[4], wv[8];
#pragma unroll
            for (int i = 0; i < 4; ++i) a[i] = Ald[rg * 4 + i][d];
#pragma unroll
            for (int j = 0; j < 8; ++j) wv[j] = Wld[d][cg * 8 + j];
#pragma unroll
            for (int i = 0; i < 4; ++i)
#pragma unroll
                for (int j = 0; j < 8; ++j)
                    acc[i][j] = fma(a[i], wv[j], acc[i][j]);
        }
    }

    if (MODE <= 1) {
        __syncthreads();
        double* scr = reinterpret_cast<double*>(smem);
#pragma unroll
        for (int j = 0; j < 8; ++j) {
            const double s = acc[0][j] + acc[1][j] + acc[2][j] + acc[3][j];
            const double q = acc[0][j]*acc[0][j] + acc[1][j]*acc[1][j]
                           + acc[2][j]*acc[2][j] + acc[3][j]*acc[3][j];
            scr[(cg * 8 + j) * 16 + rg] = s;
            scr[2048 + (cg * 8 + j) * 16 + rg] = q;
        }
        __syncthreads();
        if (tid < 128) {
            double s = 0.0, q = 0.0;
#pragma unroll
            for (int r = 0; r < 16; ++r) {
                s += scr[tid * 16 + r];
                q += scr[2048 + tid * 16 + r];
            }
            atomicAdd(&sums[col0 + tid], s);
            atomicAdd(&sums[512 + col0 + tid], q);
        }
    }

    if (MODE == 2) {
        const int p  = rb * 16 + rg;
        const int nn = p >> 6;
        const int bb = p & 63;
#pragma unroll
        for (int j = 0; j < 8; ++j) {
            const int e = col0 + cg * 8 + j;
            const double sc = scale[e];
            const double sh = shiftv[e];
            const size_t basex = (size_t)bb * (NDIM * DDIM) + (size_t)nn * DDIM + e;
            double v = 0.0;
#pragma unroll
            for (int t = 0; t < 4; ++t) {
                const double hn = fma(acc[t][j], sc, sh);
                v = v + (hn - v) / 2.0;
                const bool s = (v - 0.5) >= 0.0;
                const size_t xi = (size_t)t * BND + basex;
                out[xi] = s ? x[xi] : 0.0f;
                if (s) v = 0.0;
            }
        }
    }
}

__global__ void zero_k(double* sums)
{
    const int i = blockIdx.x * 256 + threadIdx.x;
    if (i < 1024) sums[i] = 0.0;
}

__global__ void stat_k(const double* __restrict__ sums,
                       const float* __restrict__ gamma, const float* __restrict__ beta,
                       double* __restrict__ scale, double* __restrict__ shiftv)
{
    const int e = blockIdx.x * 256 + threadIdx.x;
    if (e < 512) {
        const double mean = sums[e] * (1.0 / 65536.0);
        const double msq  = sums[512 + e] * (1.0 / 65536.0);
        const double var  = msq - mean * mean;
        const double inv  = 1.0 / sqrt(var + BN_EPS);
        const double g    = (double)gamma[e] * inv;
        scale[e]  = g;
        shiftv[e] = (double)beta[e] - mean * g;
    }
}

__global__ __launch_bounds__(256)
void lifh_k(const double* __restrict__ hbuf, const double* __restrict__ scale,
            const double* __restrict__ shiftv, const float* __restrict__ x,
            float* __restrict__ out)
{
    const size_t i = (size_t)blockIdx.x * 256 + threadIdx.x;   // < B*N*D
    const int e  = (int)(i & 511);
    const size_t p = i >> 9;
    const int nn = (int)(p >> 6);
    const int bb = (int)(p & 63);
    const double sc = scale[e];
    const double sh = shiftv[e];
    const double* hp = hbuf + p * 2048 + e;
    const size_t basex = (size_t)bb * (NDIM * DDIM) + (size_t)nn * DDIM + e;
    double v = 0.0;
#pragma unroll
    for (int t = 0; t < 4; ++t) {
        const double hn = fma(hp[(size_t)t * 512], sc, sh);
        v = v + (hn - v) / 2.0;
        const bool s = (v - 0.5) >= 0.0;
        const size_t xi = (size_t)t * BND + basex;
        out[xi] = s ? x[xi] : 0.0f;
        if (s) v = 0.0;
    }
}

extern "C" void kernel_launch(void* const* d_in, const int* in_sizes, int n_in,
                              void* d_out, int out_size, void* d_ws, size_t ws_size,
                              hipStream_t stream)
{
    const float* x     = (const float*)d_in[0];
    const float* mx    = (const float*)d_in[1];
    const float* Wm    = (const float*)d_in[2];
    const float* gamma = (const float*)d_in[3];
    const float* beta  = (const float*)d_in[4];
    float* out = (float*)d_out;

    char* ws = (char*)d_ws;
    double* sums   = (double*)ws;            // [1024]
    double* scale  = (double*)(ws + 8192);   // [512]
    double* shiftv = scale + 512;            // [512]
    double* rowmap = (double*)(ws + 16384);  // [256]
    double* hbuf   = (double*)(ws + 32768);  // [65536*512] f64 if it fits

    const size_t need_h = (size_t)32768 + (size_t)MROWS * DDIM * 8;
    const bool big = ws_size >= need_h;

    hipLaunchKernelGGL(zero_k, dim3(4), dim3(256), 0, stream, sums);

    if (big) {
        hipLaunchKernelGGL(probe_k, dim3(1), dim3(64), 0, stream, rowmap);
        hipLaunchKernelGGL(gemm3_k, dim3(2048), dim3(256), 0, stream,
                           mx, Wm, hbuf, sums, rowmap);
        hipLaunchKernelGGL(stat_k, dim3(2), dim3(256), 0, stream,
                           sums, gamma, beta, scale, shiftv);
        hipLaunchKernelGGL(lifh_k, dim3(32768), dim3(256), 0, stream,
                           hbuf, scale, shiftv, x, out);
    } else {
        hipLaunchKernelGGL((gemm_k<0>), dim3(4096), dim3(256), 0, stream,
                           mx, Wm, nullptr, sums, nullptr, nullptr, nullptr, nullptr);
        hipLaunchKernelGGL(stat_k, dim3(2), dim3(256), 0, stream,
                           sums, gamma, beta, scale, shiftv);
        hipLaunchKernelGGL((gemm_k<2>), dim3(4096), dim3(256), 0, stream,
                           mx, Wm, nullptr, nullptr, scale, shiftv, x, out);
    }
}